// Round 1
// baseline (926.336 us; speedup 1.0000x reference)
//
#include <hip/hip_runtime.h>
#include <math.h>

// GAT, 2 layers: IN=128, H=8, C=8 (layer0, concat) -> 64; layer1: 64->64, 1 head.
// All fp32. CSR-by-dst built per launch; wave-per-node online-softmax aggregation.

#define CHUNK 1024

__device__ __forceinline__ float lrelu(float v) { return v >= 0.f ? v : 0.2f * v; }
__device__ __forceinline__ float eluf(float v)  { return v > 0.f ? v : expm1f(v); }

__global__ void k_zero(int* __restrict__ p, int n) {
    int i = blockIdx.x * blockDim.x + threadIdx.x;
    if (i < n) p[i] = 0;
}

__global__ void k_count(const int* __restrict__ dst, int E, int* __restrict__ deg) {
    int i = blockIdx.x * blockDim.x + threadIdx.x;
    if (i < E) atomicAdd(&deg[dst[i]], 1);
}

// per-chunk sums
__global__ void k_scanA(const int* __restrict__ deg, int N, int* __restrict__ part) {
    __shared__ int sd[256];
    int b = blockIdx.x, t = threadIdx.x;
    int base = b * CHUNK;
    int s = 0;
    for (int i = t; i < CHUNK; i += 256) {
        int idx = base + i;
        if (idx < N) s += deg[idx];
    }
    sd[t] = s; __syncthreads();
    for (int off = 128; off > 0; off >>= 1) {
        if (t < off) sd[t] += sd[t + off];
        __syncthreads();
    }
    if (t == 0) part[b] = sd[0];
}

// exclusive scan of chunk partials (small, serial)
__global__ void k_scanB(int* __restrict__ part, int nch) {
    if (threadIdx.x == 0 && blockIdx.x == 0) {
        int run = 0;
        for (int i = 0; i < nch; i++) { int v = part[i]; part[i] = run; run += v; }
    }
}

// per-chunk exclusive scan -> row_start; cursor init
__global__ void k_scanC(const int* __restrict__ deg, int N,
                        const int* __restrict__ part,
                        int* __restrict__ row, int* __restrict__ cur) {
    __shared__ int ss[256];
    int b = blockIdx.x, t = threadIdx.x;
    int base = b * CHUNK + t * 4;
    int v[4]; int tot = 0;
    #pragma unroll
    for (int i = 0; i < 4; i++) {
        int idx = base + i;
        v[i] = (idx < N) ? deg[idx] : 0;
        tot += v[i];
    }
    ss[t] = tot; __syncthreads();
    // inclusive Hillis-Steele over 256 thread sums
    for (int off = 1; off < 256; off <<= 1) {
        int xv = (t >= off) ? ss[t - off] : 0;
        __syncthreads();
        ss[t] += xv;
        __syncthreads();
    }
    int offset = part[b] + ((t == 0) ? 0 : ss[t - 1]);
    #pragma unroll
    for (int i = 0; i < 4; i++) {
        int idx = base + i;
        if (idx <= N) {
            row[idx] = offset;
            if (idx < N) cur[idx] = offset;
        }
        offset += v[i];
    }
}

__global__ void k_fill(const int* __restrict__ src, const int* __restrict__ dst, int E,
                       int* __restrict__ cur, int* __restrict__ adj) {
    int i = blockIdx.x * blockDim.x + threadIdx.x;
    if (i < E) {
        int d = dst[i];
        int p = atomicAdd(&cur[d], 1);
        adj[p] = src[i];
    }
}

// layer0 transform: xW0 [N,64], a_src0/a_dst0 [N,8]. one wave per node, lane=col.
__global__ __launch_bounds__(256) void k_l0_transform(
    const float* __restrict__ x, const float* __restrict__ W0,
    const float* __restrict__ attS, const float* __restrict__ attD,
    int N, float* __restrict__ xw, float* __restrict__ as, float* __restrict__ ad)
{
    int n = (blockIdx.x * blockDim.x + threadIdx.x) >> 6;
    int lane = threadIdx.x & 63;
    if (n >= N) return;
    const float4* xr = (const float4*)(x + (size_t)n * 128);
    float acc = 0.f;
    #pragma unroll 8
    for (int k4 = 0; k4 < 32; k4++) {
        float4 xv = xr[k4];           // wave-broadcast (same address all lanes)
        acc = fmaf(xv.x, W0[(4 * k4 + 0) * 64 + lane], acc);
        acc = fmaf(xv.y, W0[(4 * k4 + 1) * 64 + lane], acc);
        acc = fmaf(xv.z, W0[(4 * k4 + 2) * 64 + lane], acc);
        acc = fmaf(xv.w, W0[(4 * k4 + 3) * 64 + lane], acc);
    }
    xw[(size_t)n * 64 + lane] = acc;
    float ps = acc * attS[lane];
    float pd = acc * attD[lane];
    #pragma unroll
    for (int off = 1; off < 8; off <<= 1) {   // reduce over C=8 channels in head
        ps += __shfl_xor(ps, off, 64);
        pd += __shfl_xor(pd, off, 64);
    }
    if ((lane & 7) == 0) {
        int hh = lane >> 3;
        as[(size_t)n * 8 + hh] = ps;
        ad[(size_t)n * 8 + hh] = pd;
    }
}

// layer0 aggregation: online segment-softmax, one wave per dst node.
__global__ __launch_bounds__(256) void k_l0_agg(
    const float* __restrict__ xw, const float* __restrict__ as, const float* __restrict__ ad,
    const int* __restrict__ row, const int* __restrict__ adj,
    const float* __restrict__ b0, int N, float* __restrict__ hout)
{
    int n = (blockIdx.x * blockDim.x + threadIdx.x) >> 6;
    int lane = threadIdx.x & 63;
    if (n >= N) return;
    int hh = lane >> 3;
    float adv = ad[(size_t)n * 8 + hh];
    // self-loop seeds the online softmax
    float m = lrelu(as[(size_t)n * 8 + hh] + adv);
    float denom = 1.f;
    float acc = xw[(size_t)n * 64 + lane];
    int rs = row[n], re = row[n + 1];
    for (int j = rs; j < re; j++) {
        int s = adj[j];                               // wave-broadcast
        float e = lrelu(as[(size_t)s * 8 + hh] + adv);
        float nm = fmaxf(m, e);
        float r = __expf(m - nm);
        float w = __expf(e - nm);
        acc = acc * r + w * xw[(size_t)s * 64 + lane]; // 256B coalesced gather
        denom = denom * r + w;
        m = nm;
    }
    float hv = acc / denom + b0[lane];
    hout[(size_t)n * 64 + lane] = eluf(hv);
}

// layer1 transform: hW1 [N,64], scalar a_src1/a_dst1 [N].
__global__ __launch_bounds__(256) void k_l1_transform(
    const float* __restrict__ h, const float* __restrict__ W1,
    const float* __restrict__ attS, const float* __restrict__ attD,
    int N, float* __restrict__ hw, float* __restrict__ as, float* __restrict__ ad)
{
    int n = (blockIdx.x * blockDim.x + threadIdx.x) >> 6;
    int lane = threadIdx.x & 63;
    if (n >= N) return;
    const float4* hr = (const float4*)(h + (size_t)n * 64);
    float acc = 0.f;
    #pragma unroll 8
    for (int k4 = 0; k4 < 16; k4++) {
        float4 hv = hr[k4];
        acc = fmaf(hv.x, W1[(4 * k4 + 0) * 64 + lane], acc);
        acc = fmaf(hv.y, W1[(4 * k4 + 1) * 64 + lane], acc);
        acc = fmaf(hv.z, W1[(4 * k4 + 2) * 64 + lane], acc);
        acc = fmaf(hv.w, W1[(4 * k4 + 3) * 64 + lane], acc);
    }
    hw[(size_t)n * 64 + lane] = acc;
    float ps = acc * attS[lane];
    float pd = acc * attD[lane];
    #pragma unroll
    for (int off = 1; off < 64; off <<= 1) {
        ps += __shfl_xor(ps, off, 64);
        pd += __shfl_xor(pd, off, 64);
    }
    if (lane == 0) { as[n] = ps; ad[n] = pd; }
}

// layer1 aggregation (1 head, 64 ch), mean over 1 head == identity; + b1; ELU.
__global__ __launch_bounds__(256) void k_l1_agg(
    const float* __restrict__ hw, const float* __restrict__ as, const float* __restrict__ ad,
    const int* __restrict__ row, const int* __restrict__ adj,
    const float* __restrict__ b1, int N, float* __restrict__ outp)
{
    int n = (blockIdx.x * blockDim.x + threadIdx.x) >> 6;
    int lane = threadIdx.x & 63;
    if (n >= N) return;
    float adv = ad[n];
    float m = lrelu(as[n] + adv);
    float denom = 1.f;
    float acc = hw[(size_t)n * 64 + lane];
    int rs = row[n], re = row[n + 1];
    for (int j = rs; j < re; j++) {
        int s = adj[j];
        float e = lrelu(as[s] + adv);
        float nm = fmaxf(m, e);
        float r = __expf(m - nm);
        float w = __expf(e - nm);
        acc = acc * r + w * hw[(size_t)s * 64 + lane];
        denom = denom * r + w;
        m = nm;
    }
    float ov = acc / denom + b1[lane];
    outp[(size_t)n * 64 + lane] = eluf(ov);
}

extern "C" void kernel_launch(void* const* d_in, const int* in_sizes, int n_in,
                              void* d_out, int out_size, void* d_ws, size_t ws_size,
                              hipStream_t stream)
{
    const float* x    = (const float*)d_in[0];
    const int*   ei   = (const int*)d_in[1];
    const float* W0   = (const float*)d_in[2];
    const float* aS0  = (const float*)d_in[3];
    const float* aD0  = (const float*)d_in[4];
    const float* b0   = (const float*)d_in[5];
    const float* W1   = (const float*)d_in[6];
    const float* aS1  = (const float*)d_in[7];
    const float* aD1  = (const float*)d_in[8];
    const float* b1   = (const float*)d_in[9];

    const int N = in_sizes[0] / 128;
    const int E = in_sizes[1] / 2;
    const int* srcp = ei;
    const int* dstp = ei + E;

    char* ws = (char*)d_ws;
    size_t off = 0;
    auto alloc = [&](size_t bytes) -> size_t {
        size_t o = off;
        off = (o + bytes + 255) & ~(size_t)255;
        return o;
    };
    float* B1  = (float*)(ws + alloc((size_t)N * 64 * 4));   // xW0, reused as hW1
    float* hb  = (float*)(ws + alloc((size_t)N * 64 * 4));   // layer0 output h
    float* as0 = (float*)(ws + alloc((size_t)N * 8 * 4));
    float* ad0 = (float*)(ws + alloc((size_t)N * 8 * 4));
    float* as1 = (float*)(ws + alloc((size_t)N * 4));
    float* ad1 = (float*)(ws + alloc((size_t)N * 4));
    int*   deg = (int*)(ws + alloc((size_t)N * 4));
    int*   row = (int*)(ws + alloc((size_t)(N + 1) * 4));
    int*   cur = (int*)(ws + alloc((size_t)N * 4));
    const int nch = (N + CHUNK) / CHUNK;   // == ceil((N+1)/CHUNK)
    int*  part = (int*)(ws + alloc((size_t)nch * 4));
    int*   adj = (int*)(ws + alloc((size_t)E * 4));

    // ---- CSR build (by dst) ----
    k_zero<<<(N + 255) / 256, 256, 0, stream>>>(deg, N);
    k_count<<<(E + 255) / 256, 256, 0, stream>>>(dstp, E, deg);
    k_scanA<<<nch, 256, 0, stream>>>(deg, N, part);
    k_scanB<<<1, 64, 0, stream>>>(part, nch);
    k_scanC<<<nch, 256, 0, stream>>>(deg, N, part, row, cur);
    k_fill<<<(E + 255) / 256, 256, 0, stream>>>(srcp, dstp, E, cur, adj);

    const int nodeBlocks = (N + 3) / 4;   // 4 waves/block, wave per node
    // ---- layer 0 ----
    k_l0_transform<<<nodeBlocks, 256, 0, stream>>>(x, W0, aS0, aD0, N, B1, as0, ad0);
    k_l0_agg<<<nodeBlocks, 256, 0, stream>>>(B1, as0, ad0, row, adj, b0, N, hb);
    // ---- layer 1 (B1 reused for hW1) ----
    k_l1_transform<<<nodeBlocks, 256, 0, stream>>>(hb, W1, aS1, aD1, N, B1, as1, ad1);
    k_l1_agg<<<nodeBlocks, 256, 0, stream>>>(B1, as1, ad1, row, adj, b1, N, (float*)d_out);
}

// Round 2
// 672.243 us; speedup vs baseline: 1.3780x; 1.3780x over previous
//
#include <hip/hip_runtime.h>
#include <math.h>

// GAT 2-layer. fp32. CSR-by-dst per launch.
// Transforms: W staged in LDS, 4 nodes/wave, lane=col.
// Aggregation: two-phase softmax shifted by self-loop logit (no online rescale).

#define CHUNK 1024

__device__ __forceinline__ float lrelu(float v) { return v >= 0.f ? v : 0.2f * v; }
__device__ __forceinline__ float eluf(float v)  { return v > 0.f ? v : expm1f(v); }

__global__ void k_zero(int* __restrict__ p, int n) {
    int i = blockIdx.x * blockDim.x + threadIdx.x;
    if (i < n) p[i] = 0;
}

__global__ void k_count(const int* __restrict__ dst, int E, int* __restrict__ deg) {
    int i = blockIdx.x * blockDim.x + threadIdx.x;
    if (i < E) atomicAdd(&deg[dst[i]], 1);
}

__global__ void k_scanA(const int* __restrict__ deg, int N, int* __restrict__ part) {
    __shared__ int sd[256];
    int b = blockIdx.x, t = threadIdx.x;
    int base = b * CHUNK;
    int s = 0;
    for (int i = t; i < CHUNK; i += 256) {
        int idx = base + i;
        if (idx < N) s += deg[idx];
    }
    sd[t] = s; __syncthreads();
    for (int off = 128; off > 0; off >>= 1) {
        if (t < off) sd[t] += sd[t + off];
        __syncthreads();
    }
    if (t == 0) part[b] = sd[0];
}

// exclusive scan of chunk partials — single block, LDS Hillis-Steele (nch <= 256)
__global__ void k_scanB(int* __restrict__ part, int nch) {
    __shared__ int sp[256];
    int t = threadIdx.x;
    int v = (t < nch) ? part[t] : 0;
    sp[t] = v; __syncthreads();
    for (int off = 1; off < 256; off <<= 1) {
        int xv = (t >= off) ? sp[t - off] : 0;
        __syncthreads();
        sp[t] += xv;
        __syncthreads();
    }
    if (t < nch) part[t] = sp[t] - v;
}

__global__ void k_scanC(const int* __restrict__ deg, int N,
                        const int* __restrict__ part,
                        int* __restrict__ row, int* __restrict__ cur) {
    __shared__ int ss[256];
    int b = blockIdx.x, t = threadIdx.x;
    int base = b * CHUNK + t * 4;
    int v[4]; int tot = 0;
    #pragma unroll
    for (int i = 0; i < 4; i++) {
        int idx = base + i;
        v[i] = (idx < N) ? deg[idx] : 0;
        tot += v[i];
    }
    ss[t] = tot; __syncthreads();
    for (int off = 1; off < 256; off <<= 1) {
        int xv = (t >= off) ? ss[t - off] : 0;
        __syncthreads();
        ss[t] += xv;
        __syncthreads();
    }
    int offset = part[b] + ((t == 0) ? 0 : ss[t - 1]);
    #pragma unroll
    for (int i = 0; i < 4; i++) {
        int idx = base + i;
        if (idx <= N) {
            row[idx] = offset;
            if (idx < N) cur[idx] = offset;
        }
        offset += v[i];
    }
}

__global__ void k_fill(const int* __restrict__ src, const int* __restrict__ dst, int E,
                       int* __restrict__ cur, int* __restrict__ adj) {
    int i = blockIdx.x * blockDim.x + threadIdx.x;
    if (i < E) {
        int d = dst[i];
        int p = atomicAdd(&cur[d], 1);
        adj[p] = src[i];
    }
}

// ---- transform: xw = x @ W [N,64]; att reductions. W staged in LDS.
// 4 waves/block, 4 nodes/wave, lane = output col.
template<int K, int HEADS>
__global__ __launch_bounds__(256) void k_transform(
    const float* __restrict__ xin, const float* __restrict__ W,
    const float* __restrict__ attS, const float* __restrict__ attD,
    int N, float* __restrict__ xw, float* __restrict__ as, float* __restrict__ ad)
{
    __shared__ float Wl[K * 64];
    for (int i = threadIdx.x; i < K * 64; i += 256) Wl[i] = W[i];
    __syncthreads();
    int wid = blockIdx.x * 4 + (threadIdx.x >> 6);
    int lane = threadIdx.x & 63;
    int n0 = wid * 4;
    if (n0 >= N) return;
    int cnt = min(4, N - n0);
    const float* x0 = xin + (size_t)n0 * K;
    const float* x1 = xin + (size_t)(n0 + (cnt > 1 ? 1 : 0)) * K;
    const float* x2 = xin + (size_t)(n0 + (cnt > 2 ? 2 : 0)) * K;
    const float* x3 = xin + (size_t)(n0 + (cnt > 3 ? 3 : 0)) * K;
    float a0 = 0.f, a1 = 0.f, a2 = 0.f, a3 = 0.f;
    #pragma unroll 4
    for (int k4 = 0; k4 < K / 4; k4++) {
        float4 v0 = ((const float4*)x0)[k4];
        float4 v1 = ((const float4*)x1)[k4];
        float4 v2 = ((const float4*)x2)[k4];
        float4 v3 = ((const float4*)x3)[k4];
        int kb = k4 * 256 + lane;
        float w0 = Wl[kb], w1 = Wl[kb + 64], w2 = Wl[kb + 128], w3 = Wl[kb + 192];
        a0 = fmaf(v0.x, w0, a0); a0 = fmaf(v0.y, w1, a0); a0 = fmaf(v0.z, w2, a0); a0 = fmaf(v0.w, w3, a0);
        a1 = fmaf(v1.x, w0, a1); a1 = fmaf(v1.y, w1, a1); a1 = fmaf(v1.z, w2, a1); a1 = fmaf(v1.w, w3, a1);
        a2 = fmaf(v2.x, w0, a2); a2 = fmaf(v2.y, w1, a2); a2 = fmaf(v2.z, w2, a2); a2 = fmaf(v2.w, w3, a2);
        a3 = fmaf(v3.x, w0, a3); a3 = fmaf(v3.y, w1, a3); a3 = fmaf(v3.z, w2, a3); a3 = fmaf(v3.w, w3, a3);
    }
    float accs[4] = {a0, a1, a2, a3};
    float aSl = attS[lane], aDl = attD[lane];
    #pragma unroll
    for (int i = 0; i < 4; i++) {
        if (i < cnt) {
            int n = n0 + i;
            xw[(size_t)n * 64 + lane] = accs[i];
            float ps = accs[i] * aSl, pd = accs[i] * aDl;
            if (HEADS == 8) {
                ps += __shfl_xor(ps, 1, 64); pd += __shfl_xor(pd, 1, 64);
                ps += __shfl_xor(ps, 2, 64); pd += __shfl_xor(pd, 2, 64);
                ps += __shfl_xor(ps, 4, 64); pd += __shfl_xor(pd, 4, 64);
                if ((lane & 7) == 0) {
                    as[(size_t)n * 8 + (lane >> 3)] = ps;
                    ad[(size_t)n * 8 + (lane >> 3)] = pd;
                }
            } else {
                #pragma unroll
                for (int off = 1; off < 64; off <<= 1) {
                    ps += __shfl_xor(ps, off, 64);
                    pd += __shfl_xor(pd, off, 64);
                }
                if (lane == 0) { as[n] = ps; ad[n] = pd; }
            }
        }
    }
}

// ---- layer0 aggregation (H=8, C=8). Two-phase, shift = self-loop logit.
__global__ __launch_bounds__(256) void k_agg8(
    const float* __restrict__ xw, const float* __restrict__ as, const float* __restrict__ ad,
    const int* __restrict__ row, const int* __restrict__ adj,
    const float* __restrict__ bias, int N, float* __restrict__ outp)
{
    int n = (blockIdx.x * 256 + threadIdx.x) >> 6;
    int lane = threadIdx.x & 63;
    if (n >= N) return;
    int rs = row[n], re = row[n + 1];
    // phase A: lanes = 8 edges x 8 heads
    int hh = lane & 7;
    int e8 = lane >> 3;
    float adv = ad[(size_t)n * 8 + hh];
    float shift = lrelu(as[(size_t)n * 8 + hh] + adv);  // self-loop logit
    float dsum = 0.f;
    for (int j = rs; j < re; j += 8) {
        int jj = j + e8;
        bool v = jj < re;
        int s = adj[v ? jj : rs];
        float e = lrelu(as[(size_t)s * 8 + hh] + adv);
        float p = __expf(e - shift);
        dsum += v ? p : 0.f;
    }
    dsum += __shfl_xor(dsum, 8, 64);
    dsum += __shfl_xor(dsum, 16, 64);
    dsum += __shfl_xor(dsum, 32, 64);
    float denom = 1.f + dsum;
    // phase B: lane = col; head = lane>>3. Pull per-head scalars from lane (lane>>3).
    int hb = lane >> 3;
    float advB   = __shfl(adv, hb, 64);
    float shiftB = __shfl(shift, hb, 64);
    float denomB = __shfl(denom, hb, 64);
    float acc = xw[(size_t)n * 64 + lane];  // self edge, w = exp(0) = 1
    for (int j = rs; j < re; j += 4) {
        bool v1 = j + 1 < re, v2 = j + 2 < re, v3 = j + 3 < re;
        int s0 = adj[j];
        int s1 = v1 ? adj[j + 1] : s0;
        int s2 = v2 ? adj[j + 2] : s0;
        int s3 = v3 ? adj[j + 3] : s0;
        float e0 = lrelu(as[(size_t)s0 * 8 + hb] + advB);
        float e1 = lrelu(as[(size_t)s1 * 8 + hb] + advB);
        float e2 = lrelu(as[(size_t)s2 * 8 + hb] + advB);
        float e3 = lrelu(as[(size_t)s3 * 8 + hb] + advB);
        float w0 = __expf(e0 - shiftB);
        float w1 = v1 ? __expf(e1 - shiftB) : 0.f;
        float w2 = v2 ? __expf(e2 - shiftB) : 0.f;
        float w3 = v3 ? __expf(e3 - shiftB) : 0.f;
        acc = fmaf(w0, xw[(size_t)s0 * 64 + lane], acc);
        acc = fmaf(w1, xw[(size_t)s1 * 64 + lane], acc);
        acc = fmaf(w2, xw[(size_t)s2 * 64 + lane], acc);
        acc = fmaf(w3, xw[(size_t)s3 * 64 + lane], acc);
    }
    float o = acc / denomB + bias[lane];
    outp[(size_t)n * 64 + lane] = eluf(o);
}

// ---- layer1 aggregation (1 head, 64 ch)
__global__ __launch_bounds__(256) void k_agg1(
    const float* __restrict__ hw, const float* __restrict__ as, const float* __restrict__ ad,
    const int* __restrict__ row, const int* __restrict__ adj,
    const float* __restrict__ bias, int N, float* __restrict__ outp)
{
    int n = (blockIdx.x * 256 + threadIdx.x) >> 6;
    int lane = threadIdx.x & 63;
    if (n >= N) return;
    int rs = row[n], re = row[n + 1];
    float adv = ad[n];
    float shift = lrelu(as[n] + adv);
    float dsum = 0.f;
    for (int j = rs; j < re; j += 64) {
        int jj = j + lane;
        bool v = jj < re;
        int s = adj[v ? jj : rs];
        float e = lrelu(as[s] + adv);
        float p = __expf(e - shift);
        dsum += v ? p : 0.f;
    }
    #pragma unroll
    for (int off = 1; off < 64; off <<= 1) dsum += __shfl_xor(dsum, off, 64);
    float denom = 1.f + dsum;
    float acc = hw[(size_t)n * 64 + lane];
    for (int j = rs; j < re; j += 4) {
        bool v1 = j + 1 < re, v2 = j + 2 < re, v3 = j + 3 < re;
        int s0 = adj[j];
        int s1 = v1 ? adj[j + 1] : s0;
        int s2 = v2 ? adj[j + 2] : s0;
        int s3 = v3 ? adj[j + 3] : s0;
        float e0 = lrelu(as[s0] + adv);
        float e1 = lrelu(as[s1] + adv);
        float e2 = lrelu(as[s2] + adv);
        float e3 = lrelu(as[s3] + adv);
        float w0 = __expf(e0 - shift);
        float w1 = v1 ? __expf(e1 - shift) : 0.f;
        float w2 = v2 ? __expf(e2 - shift) : 0.f;
        float w3 = v3 ? __expf(e3 - shift) : 0.f;
        acc = fmaf(w0, hw[(size_t)s0 * 64 + lane], acc);
        acc = fmaf(w1, hw[(size_t)s1 * 64 + lane], acc);
        acc = fmaf(w2, hw[(size_t)s2 * 64 + lane], acc);
        acc = fmaf(w3, hw[(size_t)s3 * 64 + lane], acc);
    }
    float o = acc / denom + bias[lane];
    outp[(size_t)n * 64 + lane] = eluf(o);
}

extern "C" void kernel_launch(void* const* d_in, const int* in_sizes, int n_in,
                              void* d_out, int out_size, void* d_ws, size_t ws_size,
                              hipStream_t stream)
{
    const float* x   = (const float*)d_in[0];
    const int*   ei  = (const int*)d_in[1];
    const float* W0  = (const float*)d_in[2];
    const float* aS0 = (const float*)d_in[3];
    const float* aD0 = (const float*)d_in[4];
    const float* b0  = (const float*)d_in[5];
    const float* W1  = (const float*)d_in[6];
    const float* aS1 = (const float*)d_in[7];
    const float* aD1 = (const float*)d_in[8];
    const float* b1  = (const float*)d_in[9];

    const int N = in_sizes[0] / 128;
    const int E = in_sizes[1] / 2;
    const int* srcp = ei;
    const int* dstp = ei + E;

    char* ws = (char*)d_ws;
    size_t off = 0;
    auto alloc = [&](size_t bytes) -> size_t {
        size_t o = off;
        off = (o + bytes + 255) & ~(size_t)255;
        return o;
    };
    float* B1  = (float*)(ws + alloc((size_t)N * 64 * 4));   // xW0, reused as hW1
    float* hb  = (float*)(ws + alloc((size_t)N * 64 * 4));   // layer0 output h
    float* as0 = (float*)(ws + alloc((size_t)N * 8 * 4));
    float* ad0 = (float*)(ws + alloc((size_t)N * 8 * 4));
    float* as1 = (float*)(ws + alloc((size_t)N * 4));
    float* ad1 = (float*)(ws + alloc((size_t)N * 4));
    int*   deg = (int*)(ws + alloc((size_t)N * 4));
    int*   row = (int*)(ws + alloc((size_t)(N + 1) * 4));
    int*   cur = (int*)(ws + alloc((size_t)N * 4));
    const int nch = (N + CHUNK) / CHUNK;
    int*  part = (int*)(ws + alloc((size_t)nch * 4));
    int*   adj = (int*)(ws + alloc((size_t)E * 4));

    // ---- CSR build (by dst) ----
    k_zero<<<(N + 255) / 256, 256, 0, stream>>>(deg, N);
    k_count<<<(E + 255) / 256, 256, 0, stream>>>(dstp, E, deg);
    k_scanA<<<nch, 256, 0, stream>>>(deg, N, part);
    k_scanB<<<1, 256, 0, stream>>>(part, nch);
    k_scanC<<<nch, 256, 0, stream>>>(deg, N, part, row, cur);
    k_fill<<<(E + 255) / 256, 256, 0, stream>>>(srcp, dstp, E, cur, adj);

    const int tfBlocks = (N + 15) / 16;   // 4 waves/block, 4 nodes/wave
    const int agBlocks = (N + 3) / 4;     // 4 waves/block, 1 node/wave
    // ---- layer 0 ----
    k_transform<128, 8><<<tfBlocks, 256, 0, stream>>>(x, W0, aS0, aD0, N, B1, as0, ad0);
    k_agg8<<<agBlocks, 256, 0, stream>>>(B1, as0, ad0, row, adj, b0, N, hb);
    // ---- layer 1 ----
    k_transform<64, 1><<<tfBlocks, 256, 0, stream>>>(hb, W1, aS1, aD1, N, B1, as1, ad1);
    k_agg1<<<agBlocks, 256, 0, stream>>>(B1, as1, ad1, row, adj, b1, N, (float*)d_out);
}

// Round 3
// 586.343 us; speedup vs baseline: 1.5799x; 1.1465x over previous
//
#include <hip/hip_runtime.h>
#include <math.h>

// GAT 2-layer fp32. CSR-by-dst per launch.
// R3: fuse [count || tf0-A] and [fill || tf0-B]; 512-thr transform blocks (8 waves
// share one LDS W tile) for full occupancy; memsetAsync for deg.

#define CHUNK 1024

__device__ __forceinline__ float lrelu(float v) { return v >= 0.f ? v : 0.2f * v; }
__device__ __forceinline__ float eluf(float v)  { return v > 0.f ? v : expm1f(v); }

// ---------------- scans ----------------
__global__ void k_scanA(const int* __restrict__ deg, int N, int* __restrict__ part) {
    __shared__ int sd[256];
    int b = blockIdx.x, t = threadIdx.x;
    int base = b * CHUNK;
    int s = 0;
    for (int i = t; i < CHUNK; i += 256) {
        int idx = base + i;
        if (idx < N) s += deg[idx];
    }
    sd[t] = s; __syncthreads();
    for (int off = 128; off > 0; off >>= 1) {
        if (t < off) sd[t] += sd[t + off];
        __syncthreads();
    }
    if (t == 0) part[b] = sd[0];
}

__global__ void k_scanB(int* __restrict__ part, int nch) {
    __shared__ int sp[256];
    int t = threadIdx.x;
    int v = (t < nch) ? part[t] : 0;
    sp[t] = v; __syncthreads();
    for (int off = 1; off < 256; off <<= 1) {
        int xv = (t >= off) ? sp[t - off] : 0;
        __syncthreads();
        sp[t] += xv;
        __syncthreads();
    }
    if (t < nch) part[t] = sp[t] - v;
}

__global__ void k_scanC(const int* __restrict__ deg, int N,
                        const int* __restrict__ part,
                        int* __restrict__ row, int* __restrict__ cur) {
    __shared__ int ss[256];
    int b = blockIdx.x, t = threadIdx.x;
    int base = b * CHUNK + t * 4;
    int v[4]; int tot = 0;
    #pragma unroll
    for (int i = 0; i < 4; i++) {
        int idx = base + i;
        v[i] = (idx < N) ? deg[idx] : 0;
        tot += v[i];
    }
    ss[t] = tot; __syncthreads();
    for (int off = 1; off < 256; off <<= 1) {
        int xv = (t >= off) ? ss[t - off] : 0;
        __syncthreads();
        ss[t] += xv;
        __syncthreads();
    }
    int offset = part[b] + ((t == 0) ? 0 : ss[t - 1]);
    #pragma unroll
    for (int i = 0; i < 4; i++) {
        int idx = base + i;
        if (idx <= N) {
            row[idx] = offset;
            if (idx < N) cur[idx] = offset;
        }
        offset += v[i];
    }
}

// ---------------- transform body (device fn) ----------------
// 512-thread block: 8 waves, 4 nodes/wave, lane = output col. W staged in LDS.
template<int K, int HEADS>
__device__ __forceinline__ void tf_body(
    int tfb, const float* __restrict__ xin, const float* __restrict__ W,
    const float* __restrict__ attS, const float* __restrict__ attD,
    int N, float* __restrict__ xw, float* __restrict__ as, float* __restrict__ ad,
    float* Wl)
{
    const float4* Wv = (const float4*)W;
    float4* Wlv = (float4*)Wl;
    for (int i = threadIdx.x; i < K * 16; i += 512) Wlv[i] = Wv[i];
    __syncthreads();
    int wave = threadIdx.x >> 6;
    int lane = threadIdx.x & 63;
    int n0 = tfb * 32 + wave * 4;
    if (n0 >= N) return;
    int cnt = min(4, N - n0);
    const float* x0 = xin + (size_t)n0 * K;
    const float* x1 = xin + (size_t)(n0 + (cnt > 1 ? 1 : 0)) * K;
    const float* x2 = xin + (size_t)(n0 + (cnt > 2 ? 2 : 0)) * K;
    const float* x3 = xin + (size_t)(n0 + (cnt > 3 ? 3 : 0)) * K;
    float a0 = 0.f, a1 = 0.f, a2 = 0.f, a3 = 0.f;
    #pragma unroll 4
    for (int k4 = 0; k4 < K / 4; k4++) {
        float4 v0 = ((const float4*)x0)[k4];
        float4 v1 = ((const float4*)x1)[k4];
        float4 v2 = ((const float4*)x2)[k4];
        float4 v3 = ((const float4*)x3)[k4];
        int kb = k4 * 256 + lane;
        float w0 = Wl[kb], w1 = Wl[kb + 64], w2 = Wl[kb + 128], w3 = Wl[kb + 192];
        a0 = fmaf(v0.x, w0, a0); a0 = fmaf(v0.y, w1, a0); a0 = fmaf(v0.z, w2, a0); a0 = fmaf(v0.w, w3, a0);
        a1 = fmaf(v1.x, w0, a1); a1 = fmaf(v1.y, w1, a1); a1 = fmaf(v1.z, w2, a1); a1 = fmaf(v1.w, w3, a1);
        a2 = fmaf(v2.x, w0, a2); a2 = fmaf(v2.y, w1, a2); a2 = fmaf(v2.z, w2, a2); a2 = fmaf(v2.w, w3, a2);
        a3 = fmaf(v3.x, w0, a3); a3 = fmaf(v3.y, w1, a3); a3 = fmaf(v3.z, w2, a3); a3 = fmaf(v3.w, w3, a3);
    }
    float accs[4] = {a0, a1, a2, a3};
    float aSl = attS[lane], aDl = attD[lane];
    #pragma unroll
    for (int i = 0; i < 4; i++) {
        if (i < cnt) {
            int n = n0 + i;
            xw[(size_t)n * 64 + lane] = accs[i];
            float ps = accs[i] * aSl, pd = accs[i] * aDl;
            if (HEADS == 8) {
                ps += __shfl_xor(ps, 1, 64); pd += __shfl_xor(pd, 1, 64);
                ps += __shfl_xor(ps, 2, 64); pd += __shfl_xor(pd, 2, 64);
                ps += __shfl_xor(ps, 4, 64); pd += __shfl_xor(pd, 4, 64);
                if ((lane & 7) == 0) {
                    as[(size_t)n * 8 + (lane >> 3)] = ps;
                    ad[(size_t)n * 8 + (lane >> 3)] = pd;
                }
            } else {
                #pragma unroll
                for (int off = 1; off < 64; off <<= 1) {
                    ps += __shfl_xor(ps, off, 64);
                    pd += __shfl_xor(pd, off, 64);
                }
                if (lane == 0) { as[n] = ps; ad[n] = pd; }
            }
        }
    }
}

// ---------------- fused: count || tf0 (part A) ----------------
__global__ __launch_bounds__(512, 8) void kA_count_tf(
    const float* __restrict__ x, const float* __restrict__ W0,
    const float* __restrict__ aS, const float* __restrict__ aD,
    int N, float* __restrict__ xw, float* __restrict__ as, float* __restrict__ ad,
    int tfBlocks,
    const int* __restrict__ dst, int E, int* __restrict__ deg, int cntBlocks)
{
    __shared__ float Wl[128 * 64];
    int b = blockIdx.x;
    int T = tfBlocks + cntBlocks;
    int lo = (int)((long long)b * tfBlocks / T);
    int hi = (int)((long long)(b + 1) * tfBlocks / T);
    if (hi > lo) {
        tf_body<128, 8>(lo, x, W0, aS, aD, N, xw, as, ad, Wl);
    } else {
        int i = (b - hi) * 512 + threadIdx.x;
        if (i < E) atomicAdd(&deg[dst[i]], 1);
    }
}

// ---------------- fused: fill || tf0 (part B) ----------------
__global__ __launch_bounds__(512, 8) void kB_fill_tf(
    const float* __restrict__ x, const float* __restrict__ W0,
    const float* __restrict__ aS, const float* __restrict__ aD,
    int N, float* __restrict__ xw, float* __restrict__ as, float* __restrict__ ad,
    int tfBlocks, int tfOffset,
    const int* __restrict__ src, const int* __restrict__ dst, int E,
    int* __restrict__ cur, int* __restrict__ adj, int filBlocks)
{
    __shared__ float Wl[128 * 64];
    int b = blockIdx.x;
    int T = tfBlocks + filBlocks;
    int lo = (int)((long long)b * tfBlocks / T);
    int hi = (int)((long long)(b + 1) * tfBlocks / T);
    if (hi > lo) {
        tf_body<128, 8>(tfOffset + lo, x, W0, aS, aD, N, xw, as, ad, Wl);
    } else {
        int i = (b - hi) * 512 + threadIdx.x;
        if (i < E) {
            int d = dst[i];
            int p = atomicAdd(&cur[d], 1);
            adj[p] = src[i];
        }
    }
}

// ---------------- standalone transform (layer 1) ----------------
__global__ __launch_bounds__(512, 8) void k_tf1(
    const float* __restrict__ h, const float* __restrict__ W1,
    const float* __restrict__ aS, const float* __restrict__ aD,
    int N, float* __restrict__ hw, float* __restrict__ as, float* __restrict__ ad)
{
    __shared__ float Wl[64 * 64];
    tf_body<64, 1>(blockIdx.x, h, W1, aS, aD, N, hw, as, ad, Wl);
}

// ---------------- layer0 aggregation ----------------
__global__ __launch_bounds__(256) void k_agg8(
    const float* __restrict__ xw, const float* __restrict__ as, const float* __restrict__ ad,
    const int* __restrict__ row, const int* __restrict__ adj,
    const float* __restrict__ bias, int N, float* __restrict__ outp)
{
    int n = (blockIdx.x * 256 + threadIdx.x) >> 6;
    int lane = threadIdx.x & 63;
    if (n >= N) return;
    int rs = row[n], re = row[n + 1];
    int hh = lane & 7;
    int e8 = lane >> 3;
    float adv = ad[(size_t)n * 8 + hh];
    float shift = lrelu(as[(size_t)n * 8 + hh] + adv);
    float dsum = 0.f;
    for (int j = rs; j < re; j += 8) {
        int jj = j + e8;
        bool v = jj < re;
        int s = adj[v ? jj : rs];
        float e = lrelu(as[(size_t)s * 8 + hh] + adv);
        float p = __expf(e - shift);
        dsum += v ? p : 0.f;
    }
    dsum += __shfl_xor(dsum, 8, 64);
    dsum += __shfl_xor(dsum, 16, 64);
    dsum += __shfl_xor(dsum, 32, 64);
    float denom = 1.f + dsum;
    int hb = lane >> 3;
    float advB   = __shfl(adv, hb, 64);
    float shiftB = __shfl(shift, hb, 64);
    float denomB = __shfl(denom, hb, 64);
    float acc = xw[(size_t)n * 64 + lane];
    for (int j = rs; j < re; j += 4) {
        bool v1 = j + 1 < re, v2 = j + 2 < re, v3 = j + 3 < re;
        int s0 = adj[j];
        int s1 = v1 ? adj[j + 1] : s0;
        int s2 = v2 ? adj[j + 2] : s0;
        int s3 = v3 ? adj[j + 3] : s0;
        float e0 = lrelu(as[(size_t)s0 * 8 + hb] + advB);
        float e1 = lrelu(as[(size_t)s1 * 8 + hb] + advB);
        float e2 = lrelu(as[(size_t)s2 * 8 + hb] + advB);
        float e3 = lrelu(as[(size_t)s3 * 8 + hb] + advB);
        float w0 = __expf(e0 - shiftB);
        float w1 = v1 ? __expf(e1 - shiftB) : 0.f;
        float w2 = v2 ? __expf(e2 - shiftB) : 0.f;
        float w3 = v3 ? __expf(e3 - shiftB) : 0.f;
        acc = fmaf(w0, xw[(size_t)s0 * 64 + lane], acc);
        acc = fmaf(w1, xw[(size_t)s1 * 64 + lane], acc);
        acc = fmaf(w2, xw[(size_t)s2 * 64 + lane], acc);
        acc = fmaf(w3, xw[(size_t)s3 * 64 + lane], acc);
    }
    float o = acc / denomB + bias[lane];
    outp[(size_t)n * 64 + lane] = eluf(o);
}

// ---------------- layer1 aggregation ----------------
__global__ __launch_bounds__(256) void k_agg1(
    const float* __restrict__ hw, const float* __restrict__ as, const float* __restrict__ ad,
    const int* __restrict__ row, const int* __restrict__ adj,
    const float* __restrict__ bias, int N, float* __restrict__ outp)
{
    int n = (blockIdx.x * 256 + threadIdx.x) >> 6;
    int lane = threadIdx.x & 63;
    if (n >= N) return;
    int rs = row[n], re = row[n + 1];
    float adv = ad[n];
    float shift = lrelu(as[n] + adv);
    float dsum = 0.f;
    for (int j = rs; j < re; j += 64) {
        int jj = j + lane;
        bool v = jj < re;
        int s = adj[v ? jj : rs];
        float e = lrelu(as[s] + adv);
        float p = __expf(e - shift);
        dsum += v ? p : 0.f;
    }
    #pragma unroll
    for (int off = 1; off < 64; off <<= 1) dsum += __shfl_xor(dsum, off, 64);
    float denom = 1.f + dsum;
    float acc = hw[(size_t)n * 64 + lane];
    for (int j = rs; j < re; j += 4) {
        bool v1 = j + 1 < re, v2 = j + 2 < re, v3 = j + 3 < re;
        int s0 = adj[j];
        int s1 = v1 ? adj[j + 1] : s0;
        int s2 = v2 ? adj[j + 2] : s0;
        int s3 = v3 ? adj[j + 3] : s0;
        float e0 = lrelu(as[s0] + adv);
        float e1 = lrelu(as[s1] + adv);
        float e2 = lrelu(as[s2] + adv);
        float e3 = lrelu(as[s3] + adv);
        float w0 = __expf(e0 - shift);
        float w1 = v1 ? __expf(e1 - shift) : 0.f;
        float w2 = v2 ? __expf(e2 - shift) : 0.f;
        float w3 = v3 ? __expf(e3 - shift) : 0.f;
        acc = fmaf(w0, hw[(size_t)s0 * 64 + lane], acc);
        acc = fmaf(w1, hw[(size_t)s1 * 64 + lane], acc);
        acc = fmaf(w2, hw[(size_t)s2 * 64 + lane], acc);
        acc = fmaf(w3, hw[(size_t)s3 * 64 + lane], acc);
    }
    float o = acc / denom + bias[lane];
    outp[(size_t)n * 64 + lane] = eluf(o);
}

extern "C" void kernel_launch(void* const* d_in, const int* in_sizes, int n_in,
                              void* d_out, int out_size, void* d_ws, size_t ws_size,
                              hipStream_t stream)
{
    const float* x   = (const float*)d_in[0];
    const int*   ei  = (const int*)d_in[1];
    const float* W0  = (const float*)d_in[2];
    const float* aS0 = (const float*)d_in[3];
    const float* aD0 = (const float*)d_in[4];
    const float* b0  = (const float*)d_in[5];
    const float* W1  = (const float*)d_in[6];
    const float* aS1 = (const float*)d_in[7];
    const float* aD1 = (const float*)d_in[8];
    const float* b1  = (const float*)d_in[9];

    const int N = in_sizes[0] / 128;
    const int E = in_sizes[1] / 2;
    const int* srcp = ei;
    const int* dstp = ei + E;

    char* ws = (char*)d_ws;
    size_t off = 0;
    auto alloc = [&](size_t bytes) -> size_t {
        size_t o = off;
        off = (o + bytes + 255) & ~(size_t)255;
        return o;
    };
    float* B1  = (float*)(ws + alloc((size_t)N * 64 * 4));   // xW0, reused as hW1
    float* hb  = (float*)(ws + alloc((size_t)N * 64 * 4));   // layer0 output h
    float* as0 = (float*)(ws + alloc((size_t)N * 8 * 4));
    float* ad0 = (float*)(ws + alloc((size_t)N * 8 * 4));
    float* as1 = (float*)(ws + alloc((size_t)N * 4));
    float* ad1 = (float*)(ws + alloc((size_t)N * 4));
    int*   deg = (int*)(ws + alloc((size_t)N * 4));
    int*   row = (int*)(ws + alloc((size_t)(N + 1) * 4));
    int*   cur = (int*)(ws + alloc((size_t)N * 4));
    const int nch = (N + CHUNK) / CHUNK;
    int*  part = (int*)(ws + alloc((size_t)nch * 4));
    int*   adj = (int*)(ws + alloc((size_t)E * 4));

    const int tfTotal = (N + 31) / 32;       // 32 nodes per 512-thr block
    const int tfA = (tfTotal + 1) / 2;
    const int tfB = tfTotal - tfA;
    const int cntB = (E + 511) / 512;

    hipMemsetAsync(deg, 0, (size_t)N * 4, stream);
    // count || tf0 part A
    kA_count_tf<<<tfA + cntB, 512, 0, stream>>>(x, W0, aS0, aD0, N, B1, as0, ad0,
                                                tfA, dstp, E, deg, cntB);
    k_scanA<<<nch, 256, 0, stream>>>(deg, N, part);
    k_scanB<<<1, 256, 0, stream>>>(part, nch);
    k_scanC<<<nch, 256, 0, stream>>>(deg, N, part, row, cur);
    // fill || tf0 part B
    kB_fill_tf<<<tfB + cntB, 512, 0, stream>>>(x, W0, aS0, aD0, N, B1, as0, ad0,
                                               tfB, tfA, srcp, dstp, E, cur, adj, cntB);

    const int agBlocks = (N + 3) / 4;
    k_agg8<<<agBlocks, 256, 0, stream>>>(B1, as0, ad0, row, adj, b0, N, hb);
    k_tf1<<<tfTotal, 512, 0, stream>>>(hb, W1, aS1, aD1, N, B1, as1, ad1);
    k_agg1<<<agBlocks, 256, 0, stream>>>(B1, as1, ad1, row, adj, b1, N, (float*)d_out);
}

// Round 4
// 558.308 us; speedup vs baseline: 1.6592x; 1.0502x over previous
//
#include <hip/hip_runtime.h>
#include <math.h>

// GAT 2-layer fp32.
// R4: CSR build = 2-phase bucket sort (dense writes, no count/scan/fill kernels).
//     Phase1 (edge binning, LDS-staged dense flushes) fused with tf0.
//     Phase2: per-bucket single-writer CSR build (L2-resident segment).
//     Transforms: 8 nodes/wave.

#define CAPS 32     // LDS staging records per bucket
#define NBMAX 128   // max buckets (N <= 131072)

__device__ __forceinline__ float lrelu(float v) { return v >= 0.f ? v : 0.2f * v; }
__device__ __forceinline__ float eluf(float v)  { return v > 0.f ? v : expm1f(v); }

// ---------------- transform body: 8 waves/block, 8 nodes/wave, lane = col ----
template<int K, int HEADS>
__device__ __forceinline__ void tf_body8(
    int tfb, const float* __restrict__ xin, const float* __restrict__ W,
    const float* __restrict__ attS, const float* __restrict__ attD,
    int N, float* __restrict__ xw, float* __restrict__ as, float* __restrict__ ad,
    float* Wl)
{
    const float4* Wv = (const float4*)W;
    float4* Wlv = (float4*)Wl;
    for (int i = threadIdx.x; i < K * 16; i += 512) Wlv[i] = Wv[i];
    __syncthreads();
    int wave = threadIdx.x >> 6;
    int lane = threadIdx.x & 63;
    int n0 = tfb * 64 + wave * 8;
    if (n0 >= N) return;
    int cnt = min(8, N - n0);
    const float4* xp[8];
    #pragma unroll
    for (int j = 0; j < 8; j++)
        xp[j] = (const float4*)(xin + (size_t)(n0 + (j < cnt ? j : 0)) * K);
    float acc[8] = {0.f,0.f,0.f,0.f,0.f,0.f,0.f,0.f};
    #pragma unroll 2
    for (int k4 = 0; k4 < K / 4; k4++) {
        float4 xv[8];
        #pragma unroll
        for (int j = 0; j < 8; j++) xv[j] = xp[j][k4];
        int kb = k4 * 256 + lane;
        float w0 = Wl[kb], w1 = Wl[kb + 64], w2 = Wl[kb + 128], w3 = Wl[kb + 192];
        #pragma unroll
        for (int j = 0; j < 8; j++) {
            acc[j] = fmaf(xv[j].x, w0, acc[j]);
            acc[j] = fmaf(xv[j].y, w1, acc[j]);
            acc[j] = fmaf(xv[j].z, w2, acc[j]);
            acc[j] = fmaf(xv[j].w, w3, acc[j]);
        }
    }
    float aSl = attS[lane], aDl = attD[lane];
    #pragma unroll
    for (int j = 0; j < 8; j++) {
        if (j < cnt) {
            int n = n0 + j;
            xw[(size_t)n * 64 + lane] = acc[j];
            float ps = acc[j] * aSl, pd = acc[j] * aDl;
            if (HEADS == 8) {
                ps += __shfl_xor(ps, 1, 64); pd += __shfl_xor(pd, 1, 64);
                ps += __shfl_xor(ps, 2, 64); pd += __shfl_xor(pd, 2, 64);
                ps += __shfl_xor(ps, 4, 64); pd += __shfl_xor(pd, 4, 64);
                if ((lane & 7) == 0) {
                    as[(size_t)n * 8 + (lane >> 3)] = ps;
                    ad[(size_t)n * 8 + (lane >> 3)] = pd;
                }
            } else {
                #pragma unroll
                for (int off = 1; off < 64; off <<= 1) {
                    ps += __shfl_xor(ps, off, 64);
                    pd += __shfl_xor(pd, off, 64);
                }
                if (lane == 0) { as[n] = ps; ad[n] = pd; }
            }
        }
    }
}

// ---------------- fused: phase1 binning || tf0 ----------------
__global__ __launch_bounds__(512, 4) void kP1(
    const float* __restrict__ x, const float* __restrict__ W0,
    const float* __restrict__ aS, const float* __restrict__ aD,
    int N, float* __restrict__ xw, float* __restrict__ as, float* __restrict__ ad,
    int tfBlocks,
    const int* __restrict__ src, const int* __restrict__ dst, int E,
    int p1Blocks, int perBlock,
    uint2* __restrict__ bucketBuf, int* __restrict__ gcur, int NB, int cap)
{
    __shared__ __align__(16) char smem[NBMAX * CAPS * 8 + NBMAX * 4];
    int b = blockIdx.x;
    int T = tfBlocks + p1Blocks;
    int lo = (int)((long long)b * tfBlocks / T);
    int hi = (int)((long long)(b + 1) * tfBlocks / T);
    if (hi > lo) {
        tf_body8<128, 8>(lo, x, W0, aS, aD, N, xw, as, ad, (float*)smem);
    } else {
        int pb = b - hi;
        uint2* stage = (uint2*)smem;
        int* scnt = (int*)(smem + NBMAX * CAPS * 8);
        int tid = threadIdx.x;
        for (int i = tid; i < NB; i += 512) scnt[i] = 0;
        __syncthreads();
        int e0 = pb * perBlock, e1 = min(E, e0 + perBlock);
        for (int base = e0; base < e1; base += 512) {
            int i = base + tid;
            if (i < e1) {
                int d = dst[i], s = src[i];
                int bk = d >> 10;
                int pos = atomicAdd(&scnt[bk], 1);
                if (pos < CAPS) {
                    stage[bk * CAPS + pos] = make_uint2((unsigned)d, (unsigned)s);
                } else {
                    int g = atomicAdd(&gcur[bk], 1);
                    bucketBuf[(size_t)bk * cap + g] = make_uint2((unsigned)d, (unsigned)s);
                }
            }
            __syncthreads();
            if (tid < NB) {
                int n = min(scnt[tid], CAPS);
                int g16 = n & ~15;
                if (g16) {
                    int gb = atomicAdd(&gcur[tid], g16);
                    uint2* gp = &bucketBuf[(size_t)tid * cap + gb];
                    for (int j = 0; j < g16; j++) gp[j] = stage[tid * CAPS + j];
                    for (int j = 0; j < n - g16; j++)
                        stage[tid * CAPS + j] = stage[tid * CAPS + g16 + j];
                    scnt[tid] = n - g16;
                } else {
                    scnt[tid] = n;
                }
            }
            __syncthreads();
        }
        if (tid < NB) {
            int n = scnt[tid];
            if (n > 0) {
                int gb = atomicAdd(&gcur[tid], n);
                uint2* gp = &bucketBuf[(size_t)tid * cap + gb];
                for (int j = 0; j < n; j++) gp[j] = stage[tid * CAPS + j];
            }
        }
    }
}

// ---------------- phase2: per-bucket CSR build ----------------
__global__ __launch_bounds__(256) void kP2(
    const uint2* __restrict__ bucketBuf, const int* __restrict__ gcur,
    int NB, int cap, int N, int* __restrict__ row, int* __restrict__ adj)
{
    __shared__ int deg[1024];
    __shared__ int curl[1024];
    __shared__ int sc[256];
    int b = blockIdx.x, tid = threadIdx.x;
    int lo = b << 10;
    int hi = min(N, lo + 1024);
    int cnt = hi - lo;
    int size = min(gcur[b], cap);
    // bucket base = sum of gcur[0..b)
    sc[tid] = (tid < b) ? gcur[tid] : 0;
    __syncthreads();
    for (int off = 128; off > 0; off >>= 1) {
        if (tid < off) sc[tid] += sc[tid + off];
        __syncthreads();
    }
    int bbase = sc[0];
    __syncthreads();
    for (int i = tid; i < 1024; i += 256) deg[i] = 0;
    __syncthreads();
    const uint2* buf = bucketBuf + (size_t)b * cap;
    for (int e = tid; e < size; e += 256) atomicAdd(&deg[buf[e].x & 1023], 1);
    __syncthreads();
    int dv[4]; int s = 0;
    #pragma unroll
    for (int j = 0; j < 4; j++) { dv[j] = deg[tid * 4 + j]; s += dv[j]; }
    sc[tid] = s; __syncthreads();
    for (int off = 1; off < 256; off <<= 1) {
        int xv = (tid >= off) ? sc[tid - off] : 0;
        __syncthreads();
        sc[tid] += xv;
        __syncthreads();
    }
    int o = (tid ? sc[tid - 1] : 0);
    #pragma unroll
    for (int j = 0; j < 4; j++) {
        int loc = tid * 4 + j;
        curl[loc] = o;
        if (loc < cnt) row[lo + loc] = bbase + o;
        o += dv[j];
    }
    if (b == NB - 1 && tid == 0) row[N] = bbase + size;
    __syncthreads();
    for (int e = tid; e < size; e += 256) {
        uint2 r = buf[e];
        int l = r.x & 1023;
        int p = atomicAdd(&curl[l], 1);
        adj[bbase + p] = (int)r.y;
    }
}

// ---------------- standalone transform (layer 1) ----------------
__global__ __launch_bounds__(512, 4) void k_tf1(
    const float* __restrict__ h, const float* __restrict__ W1,
    const float* __restrict__ aS, const float* __restrict__ aD,
    int N, float* __restrict__ hw, float* __restrict__ as, float* __restrict__ ad)
{
    __shared__ float Wl[64 * 64];
    tf_body8<64, 1>(blockIdx.x, h, W1, aS, aD, N, hw, as, ad, Wl);
}

// ---------------- layer0 aggregation ----------------
__global__ __launch_bounds__(256) void k_agg8(
    const float* __restrict__ xw, const float* __restrict__ as, const float* __restrict__ ad,
    const int* __restrict__ row, const int* __restrict__ adj,
    const float* __restrict__ bias, int N, float* __restrict__ outp)
{
    int n = (blockIdx.x * 256 + threadIdx.x) >> 6;
    int lane = threadIdx.x & 63;
    if (n >= N) return;
    int rs = row[n], re = row[n + 1];
    int hh = lane & 7;
    int e8 = lane >> 3;
    float adv = ad[(size_t)n * 8 + hh];
    float shift = lrelu(as[(size_t)n * 8 + hh] + adv);
    float dsum = 0.f;
    for (int j = rs; j < re; j += 8) {
        int jj = j + e8;
        bool v = jj < re;
        int s = adj[v ? jj : rs];
        float e = lrelu(as[(size_t)s * 8 + hh] + adv);
        float p = __expf(e - shift);
        dsum += v ? p : 0.f;
    }
    dsum += __shfl_xor(dsum, 8, 64);
    dsum += __shfl_xor(dsum, 16, 64);
    dsum += __shfl_xor(dsum, 32, 64);
    float denom = 1.f + dsum;
    int hb = lane >> 3;
    float advB   = __shfl(adv, hb, 64);
    float shiftB = __shfl(shift, hb, 64);
    float denomB = __shfl(denom, hb, 64);
    float acc = xw[(size_t)n * 64 + lane];
    for (int j = rs; j < re; j += 4) {
        bool v1 = j + 1 < re, v2 = j + 2 < re, v3 = j + 3 < re;
        int s0 = adj[j];
        int s1 = v1 ? adj[j + 1] : s0;
        int s2 = v2 ? adj[j + 2] : s0;
        int s3 = v3 ? adj[j + 3] : s0;
        float e0 = lrelu(as[(size_t)s0 * 8 + hb] + advB);
        float e1 = lrelu(as[(size_t)s1 * 8 + hb] + advB);
        float e2 = lrelu(as[(size_t)s2 * 8 + hb] + advB);
        float e3 = lrelu(as[(size_t)s3 * 8 + hb] + advB);
        float w0 = __expf(e0 - shiftB);
        float w1 = v1 ? __expf(e1 - shiftB) : 0.f;
        float w2 = v2 ? __expf(e2 - shiftB) : 0.f;
        float w3 = v3 ? __expf(e3 - shiftB) : 0.f;
        acc = fmaf(w0, xw[(size_t)s0 * 64 + lane], acc);
        acc = fmaf(w1, xw[(size_t)s1 * 64 + lane], acc);
        acc = fmaf(w2, xw[(size_t)s2 * 64 + lane], acc);
        acc = fmaf(w3, xw[(size_t)s3 * 64 + lane], acc);
    }
    float o = acc / denomB + bias[lane];
    outp[(size_t)n * 64 + lane] = eluf(o);
}

// ---------------- layer1 aggregation ----------------
__global__ __launch_bounds__(256) void k_agg1(
    const float* __restrict__ hw, const float* __restrict__ as, const float* __restrict__ ad,
    const int* __restrict__ row, const int* __restrict__ adj,
    const float* __restrict__ bias, int N, float* __restrict__ outp)
{
    int n = (blockIdx.x * 256 + threadIdx.x) >> 6;
    int lane = threadIdx.x & 63;
    if (n >= N) return;
    int rs = row[n], re = row[n + 1];
    float adv = ad[n];
    float shift = lrelu(as[n] + adv);
    float dsum = 0.f;
    for (int j = rs; j < re; j += 64) {
        int jj = j + lane;
        bool v = jj < re;
        int s = adj[v ? jj : rs];
        float e = lrelu(as[s] + adv);
        float p = __expf(e - shift);
        dsum += v ? p : 0.f;
    }
    #pragma unroll
    for (int off = 1; off < 64; off <<= 1) dsum += __shfl_xor(dsum, off, 64);
    float denom = 1.f + dsum;
    float acc = hw[(size_t)n * 64 + lane];
    for (int j = rs; j < re; j += 4) {
        bool v1 = j + 1 < re, v2 = j + 2 < re, v3 = j + 3 < re;
        int s0 = adj[j];
        int s1 = v1 ? adj[j + 1] : s0;
        int s2 = v2 ? adj[j + 2] : s0;
        int s3 = v3 ? adj[j + 3] : s0;
        float e0 = lrelu(as[s0] + adv);
        float e1 = lrelu(as[s1] + adv);
        float e2 = lrelu(as[s2] + adv);
        float e3 = lrelu(as[s3] + adv);
        float w0 = __expf(e0 - shift);
        float w1 = v1 ? __expf(e1 - shift) : 0.f;
        float w2 = v2 ? __expf(e2 - shift) : 0.f;
        float w3 = v3 ? __expf(e3 - shift) : 0.f;
        acc = fmaf(w0, hw[(size_t)s0 * 64 + lane], acc);
        acc = fmaf(w1, hw[(size_t)s1 * 64 + lane], acc);
        acc = fmaf(w2, hw[(size_t)s2 * 64 + lane], acc);
        acc = fmaf(w3, hw[(size_t)s3 * 64 + lane], acc);
    }
    float o = acc / denom + bias[lane];
    outp[(size_t)n * 64 + lane] = eluf(o);
}

extern "C" void kernel_launch(void* const* d_in, const int* in_sizes, int n_in,
                              void* d_out, int out_size, void* d_ws, size_t ws_size,
                              hipStream_t stream)
{
    const float* x   = (const float*)d_in[0];
    const int*   ei  = (const int*)d_in[1];
    const float* W0  = (const float*)d_in[2];
    const float* aS0 = (const float*)d_in[3];
    const float* aD0 = (const float*)d_in[4];
    const float* b0  = (const float*)d_in[5];
    const float* W1  = (const float*)d_in[6];
    const float* aS1 = (const float*)d_in[7];
    const float* aD1 = (const float*)d_in[8];
    const float* b1  = (const float*)d_in[9];

    const int N = in_sizes[0] / 128;
    const int E = in_sizes[1] / 2;
    const int* srcp = ei;
    const int* dstp = ei + E;

    const int NB  = (N + 1023) >> 10;      // dst buckets of 1024 nodes (<= NBMAX)
    const int cap = E / NB + 4096;         // per-bucket record capacity

    char* ws = (char*)d_ws;
    size_t off = 0;
    auto alloc = [&](size_t bytes) -> size_t {
        size_t o = off;
        off = (o + bytes + 255) & ~(size_t)255;
        return o;
    };
    float* B1  = (float*)(ws + alloc((size_t)N * 64 * 4));      // xW0, reused as hW1
    // hb (layer0 output) overlays bucketBuf: bucketBuf dead after kP2, hb written by agg8
    size_t hbBytes = (size_t)N * 64 * 4;
    size_t bkBytes = (size_t)NB * cap * 8;
    char*  region  = ws + alloc(hbBytes > bkBytes ? hbBytes : bkBytes);
    float* hb        = (float*)region;
    uint2* bucketBuf = (uint2*)region;
    float* as0 = (float*)(ws + alloc((size_t)N * 8 * 4));
    float* ad0 = (float*)(ws + alloc((size_t)N * 8 * 4));
    float* as1 = (float*)(ws + alloc((size_t)N * 4));
    float* ad1 = (float*)(ws + alloc((size_t)N * 4));
    int*   row = (int*)(ws + alloc((size_t)(N + 1) * 4));
    int*   adj = (int*)(ws + alloc((size_t)E * 4));
    int*  gcur = (int*)(ws + alloc((size_t)NB * 4));

    const int tfBlocks = (N + 63) / 64;    // 8 waves x 8 nodes per 512-thr block
    const int p1Blocks = 1024;
    const int perBlock = (E + p1Blocks - 1) / p1Blocks;

    hipMemsetAsync(gcur, 0, (size_t)NB * 4, stream);
    kP1<<<tfBlocks + p1Blocks, 512, 0, stream>>>(
        x, W0, aS0, aD0, N, B1, as0, ad0, tfBlocks,
        srcp, dstp, E, p1Blocks, perBlock, bucketBuf, gcur, NB, cap);
    kP2<<<NB, 256, 0, stream>>>(bucketBuf, gcur, NB, cap, N, row, adj);

    const int agBlocks = (N + 3) / 4;
    k_agg8<<<agBlocks, 256, 0, stream>>>(B1, as0, ad0, row, adj, b0, N, hb);
    k_tf1<<<tfBlocks, 512, 0, stream>>>(hb, W1, aS1, aD1, N, B1, as1, ad1);
    k_agg1<<<agBlocks, 256, 0, stream>>>(B1, as1, ad1, row, adj, b1, N, (float*)d_out);
}